// Round 1
// baseline (4345.734 us; speedup 1.0000x reference)
//
#include <hip/hip_runtime.h>
#include <hip/hip_bf16.h>
#include <stdint.h>

typedef __bf16 bf16_t;
typedef __attribute__((ext_vector_type(8))) __bf16 bf16x8;
typedef __attribute__((ext_vector_type(4))) __bf16 bf16x4;
typedef __attribute__((ext_vector_type(4))) float f32x4;

#define E_DIM 1024
#define NHEAD 16
#define HDIM 64
#define FF 4096
#define BSZ 2048
#define TLEN 2
#define VOCAB 32000
#define NLAYER 12
#define NTOK (BSZ*TLEN)   // 4096

__device__ __forceinline__ void async_ld16(const void* g, void* l) {
  __builtin_amdgcn_global_load_lds((__attribute__((address_space(1))) void*)g,
                                   (__attribute__((address_space(3))) void*)l,
                                   16, 0, 0);
}

// ---------------- runtime dtype detection ----------------
// If storage is bf16, the LOW 16 bits of a packed u32 are a real bf16 whose
// exponent lands in a plausible band for N(0, 1/32) data. If storage is f32,
// the low 16 bits are mantissa noise (plausible only ~15% of the time).
__global__ __launch_bounds__(256) void detect_kernel(const uint32_t* __restrict__ raw,
                                                     int* __restrict__ flag) {
  __shared__ int cnt;
  const int tid = threadIdx.x;
  if (tid == 0) cnt = 0;
  __syncthreads();
  uint32_t v = raw[tid * 997 + 13];
  uint32_t lo = v & 0xFFFFu;
  int e = (int)((lo >> 7) & 0xFFu);
  int plausible = (e >= 96 && e <= 134) ? 1 : 0;
  atomicAdd(&cnt, plausible);
  __syncthreads();
  if (tid == 0) *flag = (cnt >= 128) ? 1 : 0;   // 1 = bf16 storage, 0 = f32
}

// ---------------- transpose + convert to bf16 ----------------
// src: [batch][K][N] (f32 or bf16 per *flag) -> dst: [batch][N][K] bf16
// out offset per batch bz: (bz/bmod)*out_hi + (bz%bmod)*out_lo
__global__ __launch_bounds__(256) void transpose_convert_kernel(
    const void* __restrict__ src, bf16_t* __restrict__ dst,
    int K, int N,
    long long in_bstride, long long out_hi, long long out_lo, int bmod,
    const int* __restrict__ flag) {
  __shared__ float tile[64][65];
  const int bz = blockIdx.z;
  const long long in_base = (long long)bz * in_bstride;
  const long long out_base = (long long)(bz / bmod) * out_hi + (long long)(bz % bmod) * out_lo;
  const int n0 = blockIdx.x * 64, k0 = blockIdx.y * 64;
  const int lane_n = threadIdx.x & 63;
  const int kq = threadIdx.x >> 6;
  const int bf = *flag;
  const float* sf = (const float*)src;
  const bf16_t* sb = (const bf16_t*)src;
#pragma unroll
  for (int r = 0; r < 16; ++r) {
    int kk = r * 4 + kq;
    long long idx = in_base + (long long)(k0 + kk) * N + (n0 + lane_n);
    tile[kk][lane_n] = bf ? (float)sb[idx] : sf[idx];
  }
  __syncthreads();
#pragma unroll
  for (int r = 0; r < 16; ++r) {
    int nn = r * 4 + kq;
    long long odx = out_base + (long long)(n0 + nn) * K + (k0 + lane_n);
    dst[odx] = (bf16_t)tile[lane_n][nn];
  }
}

// ---------------- embedding: x = emb[tok] + pos[t] ----------------
__global__ __launch_bounds__(256) void embed_kernel(
    const int* __restrict__ tokens, const void* __restrict__ emb,
    const void* __restrict__ pos, float* __restrict__ xF,
    bf16_t* __restrict__ xB, const int* __restrict__ flag) {
  const int row = blockIdx.x;         // b*2 + t
  const int tok = tokens[row];
  const int t = row & 1;
  const int c = threadIdx.x * 4;
  const int bf = *flag;
  float e0, e1, e2, e3, p0, p1, p2, p3;
  if (bf) {
    bf16x4 ev = *(const bf16x4*)((const bf16_t*)emb + (size_t)tok * E_DIM + c);
    bf16x4 pv = *(const bf16x4*)((const bf16_t*)pos + (size_t)t * E_DIM + c);
    e0 = (float)ev[0]; e1 = (float)ev[1]; e2 = (float)ev[2]; e3 = (float)ev[3];
    p0 = (float)pv[0]; p1 = (float)pv[1]; p2 = (float)pv[2]; p3 = (float)pv[3];
  } else {
    float4 ev = *(const float4*)((const float*)emb + (size_t)tok * E_DIM + c);
    float4 pv = *(const float4*)((const float*)pos + (size_t)t * E_DIM + c);
    e0 = ev.x; e1 = ev.y; e2 = ev.z; e3 = ev.w;
    p0 = pv.x; p1 = pv.y; p2 = pv.z; p3 = pv.w;
  }
  float4 o; o.x = e0 + p0; o.y = e1 + p1; o.z = e2 + p2; o.w = e3 + p3;
  *(float4*)(xF + (size_t)row * E_DIM + c) = o;
  bf16x4 ob; ob[0] = (bf16_t)o.x; ob[1] = (bf16_t)o.y; ob[2] = (bf16_t)o.z; ob[3] = (bf16_t)o.w;
  *(bf16x4*)(xB + (size_t)row * E_DIM + c) = ob;
}

// ---------------- attention (T=2): one wave per (b,h) ----------------
__global__ __launch_bounds__(256) void attn_kernel(const bf16_t* __restrict__ qkv,
                                                   bf16_t* __restrict__ out) {
  const int idx = blockIdx.x * 4 + (threadIdx.x >> 6);  // b*16 + h
  const int lane = threadIdx.x & 63;
  const int b = idx >> 4, h = idx & 15;
  const bf16_t* base = qkv + (size_t)(b * 2) * 3072;
  const int co = h * 64 + lane;
  float q0 = (float)base[co];
  float k0 = (float)base[1024 + co];
  float v0 = (float)base[2048 + co];
  float q1 = (float)base[3072 + co];
  float k1 = (float)base[3072 + 1024 + co];
  float v1 = (float)base[3072 + 2048 + co];
  float s00 = q0 * k0, s01 = q0 * k1, s10 = q1 * k0, s11 = q1 * k1;
#pragma unroll
  for (int o = 32; o > 0; o >>= 1) {
    s00 += __shfl_xor(s00, o, 64);
    s01 += __shfl_xor(s01, o, 64);
    s10 += __shfl_xor(s10, o, 64);
    s11 += __shfl_xor(s11, o, 64);
  }
  const float sc = 0.125f;  // 1/sqrt(64)
  s00 *= sc; s01 *= sc; s10 *= sc; s11 *= sc;
  float m0 = fmaxf(s00, s01), m1 = fmaxf(s10, s11);
  float e00 = __expf(s00 - m0), e01 = __expf(s01 - m0);
  float e10 = __expf(s10 - m1), e11 = __expf(s11 - m1);
  float p00 = e00 / (e00 + e01), p01 = e01 / (e00 + e01);
  float p10 = e10 / (e10 + e11), p11 = e11 / (e10 + e11);
  out[(size_t)(b * 2) * 1024 + co] = (bf16_t)(p00 * v0 + p01 * v1);
  out[(size_t)(b * 2 + 1) * 1024 + co] = (bf16_t)(p10 * v0 + p11 * v1);
}

// ---------------- GEMM: C = act(A @ B^T + bias) + resid ----------------
// A: M x K bf16 (row stride lda). BT: N x K bf16 row-major.
// m97 structure: 128x128 tile, BK=32, 4 waves x 4x4 mfma_f32_16x16x32_bf16,
// global_load_lds width=16 staging, 2 barriers per K-step.
__global__ __launch_bounds__(256, 2) void gemm_kernel(
    const bf16_t* __restrict__ A, int lda,
    const bf16_t* __restrict__ BT,
    float* __restrict__ outF, bf16_t* __restrict__ outB,
    void* __restrict__ outDyn,
    const float* __restrict__ resid,
    const void* __restrict__ biasRaw, int biasOff,
    int M, int N, int K, int doRelu,
    const int* __restrict__ flag) {
  __shared__ bf16_t As[128 * 32] __attribute__((aligned(16)));
  __shared__ bf16_t Bs[128 * 32] __attribute__((aligned(16)));
  const int tid = threadIdx.x;
  const int lane = tid & 63;
  const int w = tid >> 6;
  const int bn = blockIdx.x * 128;
  const int bm = blockIdx.y * 128;
  const int wm = (w >> 1) * 64;
  const int wn = (w & 1) * 64;
  const int quad = lane >> 4;
  const int l16 = lane & 15;

  // staging: wave w stages A rows [w*32, w*32+32) and BT rows likewise;
  // per call: 16 rows, lane -> row = lane/4, k-off = (lane&3)*8 (16B/lane)
  const int srow = w * 32 + (lane >> 2);
  const int skoff = (lane & 3) * 8;
  const bf16_t* Ag = A + (size_t)(bm + srow) * lda + skoff;
  const bf16_t* Bg = BT + (size_t)(bn + srow) * K + skoff;
  bf16_t* AsDst0 = As + (w * 32) * 32;
  bf16_t* BsDst0 = Bs + (w * 32) * 32;

  f32x4 acc[4][4] = {};

  for (int k0 = 0; k0 < K; k0 += 32) {
    __syncthreads();  // previous tiles fully consumed
    async_ld16(Ag + k0, AsDst0);
    async_ld16(Ag + k0 + (size_t)16 * lda, AsDst0 + 16 * 32);
    async_ld16(Bg + k0, BsDst0);
    async_ld16(Bg + k0 + (size_t)16 * K, BsDst0 + 16 * 32);
    __syncthreads();  // vmcnt(0) drain -> LDS visible
    bf16x8 a[4], b[4];
#pragma unroll
    for (int i = 0; i < 4; ++i)
      a[i] = *(const bf16x8*)&As[(wm + i * 16 + l16) * 32 + quad * 8];
#pragma unroll
    for (int j = 0; j < 4; ++j)
      b[j] = *(const bf16x8*)&Bs[(wn + j * 16 + l16) * 32 + quad * 8];
#pragma unroll
    for (int i = 0; i < 4; ++i)
#pragma unroll
      for (int j = 0; j < 4; ++j)
        acc[i][j] = __builtin_amdgcn_mfma_f32_16x16x32_bf16(a[i], b[j], acc[i][j], 0, 0, 0);
  }

  // epilogue: bias -> relu -> residual -> store (f32 / bf16 / flag-dtype)
  const int dt = *flag;
  const bf16_t* biasB = nullptr;
  const float* biasF = nullptr;
  if (biasRaw) {
    if (dt) biasB = (const bf16_t*)biasRaw + biasOff;
    else biasF = (const float*)biasRaw + biasOff;
  }
#pragma unroll
  for (int i = 0; i < 4; ++i) {
#pragma unroll
    for (int j = 0; j < 4; ++j) {
      const int col = bn + wn + j * 16 + l16;
      float bv = 0.f;
      if (biasRaw) bv = biasB ? (float)biasB[col] : biasF[col];
#pragma unroll
      for (int r = 0; r < 4; ++r) {
        const int row = bm + wm + i * 16 + quad * 4 + r;
        float v = acc[i][j][r] + bv;
        if (doRelu) v = fmaxf(v, 0.f);
        const size_t o = (size_t)row * N + col;
        if (resid) v += resid[o];
        if (outF) outF[o] = v;
        if (outB) outB[o] = (bf16_t)v;
        if (outDyn) {
          if (dt) ((bf16_t*)outDyn)[o] = (bf16_t)v;
          else ((float*)outDyn)[o] = v;
        }
      }
    }
  }
}

extern "C" void kernel_launch(void* const* d_in, const int* in_sizes, int n_in,
                              void* d_out, int out_size, void* d_ws, size_t ws_size,
                              hipStream_t stream) {
  const int* tokens = (const int*)d_in[0];
  const void* emb = d_in[1];
  const void* pos = d_in[2];
  const void* Wq = d_in[3];
  const void* Wk = d_in[4];
  const void* Wv = d_in[5];
  const void* Wo = d_in[6];
  const void* W1 = d_in[7];
  const void* b1 = d_in[8];
  const void* W2 = d_in[9];
  const void* b2 = d_in[10];
  const void* unemb = d_in[11];

  char* ws = (char*)d_ws;
  size_t off = 0;
  auto alloc = [&](size_t bytes) -> char* {
    char* p = ws + off;
    off += (bytes + 255) & ~(size_t)255;
    return p;
  };
  bf16_t* Wqkv = (bf16_t*)alloc((size_t)NLAYER * 3072 * 1024 * 2);  // [l][n=3072][k=1024]
  bf16_t* WoT  = (bf16_t*)alloc((size_t)NLAYER * 1024 * 1024 * 2);  // [l][n][k]
  bf16_t* W1T  = (bf16_t*)alloc((size_t)NLAYER * 4096 * 1024 * 2);  // [l][4096][1024]
  bf16_t* W2T  = (bf16_t*)alloc((size_t)NLAYER * 1024 * 4096 * 2);  // [l][1024][4096]
  bf16_t* UT   = (bf16_t*)alloc((size_t)VOCAB * 1024 * 2);          // [32000][1024]
  float*  xF   = (float*)alloc((size_t)NTOK * E_DIM * 4);
  bf16_t* xb0  = (bf16_t*)alloc((size_t)NTOK * E_DIM * 2);
  bf16_t* xb1  = (bf16_t*)alloc((size_t)NTOK * E_DIM * 2);
  bf16_t* qkvB = (bf16_t*)alloc((size_t)NTOK * 3072 * 2);
  bf16_t* attO = (bf16_t*)alloc((size_t)NTOK * E_DIM * 2);
  bf16_t* hB   = (bf16_t*)alloc((size_t)NTOK * FF * 2);
  int* flag    = (int*)alloc(256);
  (void)ws_size; (void)in_sizes; (void)n_in; (void)out_size;

  detect_kernel<<<1, 256, 0, stream>>>((const uint32_t*)emb, flag);

  // Weight conversion (transpose to N x K, bf16).
  // Wq/Wk/Wv: per (l,h) transpose 1024(e) x 64(o); out n = which*1024 + h*64 + o
  transpose_convert_kernel<<<dim3(1, 16, 192), 256, 0, stream>>>(
      Wq, Wqkv + 0,       1024, 64, 65536LL, 3145728LL, 65536LL, 16, flag);
  transpose_convert_kernel<<<dim3(1, 16, 192), 256, 0, stream>>>(
      Wk, Wqkv + 1048576, 1024, 64, 65536LL, 3145728LL, 65536LL, 16, flag);
  transpose_convert_kernel<<<dim3(1, 16, 192), 256, 0, stream>>>(
      Wv, Wqkv + 2097152, 1024, 64, 65536LL, 3145728LL, 65536LL, 16, flag);
  transpose_convert_kernel<<<dim3(16, 16, 12), 256, 0, stream>>>(
      Wo, WoT, 1024, 1024, 1048576LL, 1048576LL, 0LL, 1, flag);
  transpose_convert_kernel<<<dim3(64, 16, 12), 256, 0, stream>>>(
      W1, W1T, 1024, 4096, 4194304LL, 4194304LL, 0LL, 1, flag);
  transpose_convert_kernel<<<dim3(16, 64, 12), 256, 0, stream>>>(
      W2, W2T, 4096, 1024, 4194304LL, 4194304LL, 0LL, 1, flag);
  transpose_convert_kernel<<<dim3(500, 16, 1), 256, 0, stream>>>(
      unemb, UT, 1024, 32000, 0LL, 0LL, 0LL, 1, flag);

  embed_kernel<<<NTOK, 256, 0, stream>>>(tokens, emb, pos, xF, xb0, flag);

  for (int l = 0; l < NLAYER; ++l) {
    // qkv = x @ Wqkv   (4096 x 1024 x 3072)
    gemm_kernel<<<dim3(24, 32), 256, 0, stream>>>(
        xb0, E_DIM, Wqkv + (size_t)l * 3145728,
        nullptr, qkvB, nullptr, nullptr, nullptr, 0,
        NTOK, 3072, 1024, 0, flag);
    attn_kernel<<<8192, 256, 0, stream>>>(qkvB, attO);
    // x = attn @ Wo + x  (writes xF in place + bf16 copy to xb1)
    gemm_kernel<<<dim3(8, 32), 256, 0, stream>>>(
        attO, E_DIM, WoT + (size_t)l * 1048576,
        xF, xb1, nullptr, xF, nullptr, 0,
        NTOK, 1024, 1024, 0, flag);
    // h = relu(x @ W1 + b1)  (4096 x 1024 x 4096)
    gemm_kernel<<<dim3(32, 32), 256, 0, stream>>>(
        xb1, E_DIM, W1T + (size_t)l * 4194304,
        nullptr, hB, nullptr, nullptr, b1, l * 4096,
        NTOK, 4096, 1024, 1, flag);
    // x = relu(h @ W2 + b2) + x  (4096 x 4096 x 1024)
    gemm_kernel<<<dim3(8, 32), 256, 0, stream>>>(
        hB, FF, W2T + (size_t)l * 4194304,
        xF, xb0, nullptr, xF, b2, l * 1024,
        NTOK, 1024, 4096, 1, flag);
  }

  // logits = x[:, -1, :] @ unembed : A rows are odd rows of x -> base + E, stride 2E
  gemm_kernel<<<dim3(250, 16), 256, 0, stream>>>(
      xb0 + E_DIM, 2 * E_DIM, UT,
      nullptr, nullptr, d_out, nullptr, nullptr, 0,
      BSZ, VOCAB, 1024, 0, flag);
}